// Round 3
// baseline (715.613 us; speedup 1.0000x reference)
//
#include <hip/hip_runtime.h>

// ---------------------------------------------------------------------------
// PathAttention block on MI355X. bf16 MFMA for all GEMM-shaped work.
// Needs ~175 MB of d_ws.
// ---------------------------------------------------------------------------

typedef __attribute__((ext_vector_type(4))) float f32x4;
typedef __attribute__((ext_vector_type(8))) short bf16x8;
typedef __attribute__((ext_vector_type(4))) short bf16x4;

#define MFMA(a, b, c) __builtin_amdgcn_mfma_f32_16x16x32_bf16(a, b, c, 0, 0, 0)

static __device__ __forceinline__ short f2bf(float x) {
  union { float f; unsigned u; } v; v.f = x;
  unsigned r = v.u + 0x7FFFu + ((v.u >> 16) & 1u);
  return (short)(r >> 16);
}
static __device__ __forceinline__ float bf2f(short b) {
  union { unsigned u; float f; } v;
  v.u = ((unsigned)(unsigned short)b) << 16;
  return v.f;
}

// ------------------------------ weight convert -----------------------------
__global__ void k_cvt(const float* __restrict__ s, short* __restrict__ d, int n) {
  int i = blockIdx.x * 256 + threadIdx.x;
  if (i < n) d[i] = f2bf(s[i]);
}

// ------------------------------ cnt histogram ------------------------------
__global__ void k_cnt(const int* __restrict__ pinv, float* __restrict__ cnt, int M) {
  int i = blockIdx.x * 256 + threadIdx.x;
  if (i < M) atomicAdd(&cnt[pinv[i]], 1.0f);
}

// --------------------- K1: LN(feat) -> qkv GEMM (bf16 out) -----------------
// block: 256 thr, 64 rows x 384 cols. LDS h tile swizzled, out staged for
// coalesced store.
__global__ __launch_bounds__(256) void k1_ln_qkv(
    const float* __restrict__ feat, const float* __restrict__ g1,
    const float* __restrict__ b1, const short* __restrict__ wq,
    const float* __restrict__ bq, short* __restrict__ qkvb) {
  __shared__ short h_lds[64 * 128];
  __shared__ short o_st[64 * 384];
  const int blk = blockIdx.x, t = threadIdx.x;
  {
    const int r = t >> 2, quad = t & 3;
    const float* fp = feat + (size_t)(blk * 64 + r) * 128 + quad * 32;
    float vals[32];
    float s = 0.f, s2 = 0.f;
#pragma unroll
    for (int i = 0; i < 8; i++) {
      f32x4 v = *(const f32x4*)(fp + i * 4);
#pragma unroll
      for (int j = 0; j < 4; j++) { float x = v[j]; vals[i * 4 + j] = x; s += x; s2 += x * x; }
    }
    s += __shfl_xor(s, 1);  s += __shfl_xor(s, 2);
    s2 += __shfl_xor(s2, 1); s2 += __shfl_xor(s2, 2);
    float mean = s * (1.f / 128.f);
    float rstd = rsqrtf(s2 * (1.f / 128.f) - mean * mean + 1e-5f);
    const int sw = (r & 7) << 4;
#pragma unroll
    for (int gi = 0; gi < 4; gi++) {
      bf16x8 wv;
#pragma unroll
      for (int j = 0; j < 8; j++) {
        int c = quad * 32 + gi * 8 + j;
        wv[j] = f2bf((vals[gi * 8 + j] - mean) * rstd * g1[c] + b1[c]);
      }
      *(bf16x8*)((char*)h_lds + r * 256 + ((quad * 64 + gi * 16) ^ sw)) = wv;
    }
  }
  __syncthreads();
  const int wave = t >> 6, lane = t & 63, u = lane & 15, g = lane >> 4;
  f32x4 acc[4][6];
  f32x4 zz = {0.f, 0.f, 0.f, 0.f};
#pragma unroll
  for (int a = 0; a < 4; a++)
#pragma unroll
    for (int b = 0; b < 6; b++) acc[a][b] = zz;
#pragma unroll
  for (int kk = 0; kk < 4; kk++) {
    bf16x8 af[4];
#pragma unroll
    for (int rt = 0; rt < 4; rt++)
      af[rt] = *(const bf16x8*)((char*)h_lds + (rt * 16 + u) * 256 +
                                ((kk * 64 + g * 16) ^ ((u & 7) << 4)));
    bf16x8 bfr[6];
#pragma unroll
    for (int ct = 0; ct < 6; ct++) {
      int col = wave * 96 + ct * 16 + u;
      bfr[ct] = *(const bf16x8*)(wq + (size_t)col * 128 + kk * 32 + g * 8);
    }
#pragma unroll
    for (int rt = 0; rt < 4; rt++)
#pragma unroll
      for (int ct = 0; ct < 6; ct++) acc[rt][ct] = MFMA(af[rt], bfr[ct], acc[rt][ct]);
  }
#pragma unroll
  for (int rt = 0; rt < 4; rt++)
#pragma unroll
    for (int ct = 0; ct < 6; ct++) {
      int col = wave * 96 + ct * 16 + u;
      float bias = bq[col];
#pragma unroll
      for (int reg = 0; reg < 4; reg++) {
        int rowl = rt * 16 + 4 * g + reg;
        o_st[rowl * 384 + col] = f2bf(acc[rt][ct][reg] + bias);
      }
    }
  __syncthreads();
  for (int idx = t; idx < 3072; idx += 256) {
    int rr = idx / 48, c8 = idx % 48;
    *(bf16x8*)(qkvb + ((size_t)blk * 64 + rr) * 384 + c8 * 8) =
        *(const bf16x8*)(o_st + rr * 384 + c8 * 8);
  }
}

// --------------------- K2: windowed attention per 48-block -----------------
// block: 512 thr (8 waves = 8 heads). Gather+RoPE stage -> swapped QK^T mfma
// -> in-register softmax -> PV mfma (V staged transposed) -> write canonical
// rows compacted by m.
__global__ __launch_bounds__(512) void k2_attn(
    const short* __restrict__ qkv, const float* __restrict__ cosb,
    const float* __restrict__ sinb, const int* __restrict__ pinv,
    const int* __restrict__ padv, const int* __restrict__ unpadv,
    short* __restrict__ ocmp) {
  __shared__ short q_lds[48 * 128];
  __shared__ short k_lds[48 * 128];
  __shared__ short vT[8 * 16 * 64];  // [h][d][j], j padded to 64
  __shared__ short o_lds[48 * 128];
  __shared__ int midx_s[48];
  __shared__ int gidx_s[48];
  __shared__ int canon_s[48];
  __shared__ float cs_s[48 * 8];
  __shared__ float sn_s[48 * 8];

  const int w = blockIdx.x;
  const int t = threadIdx.x;

  if (t < 48) {
    int pp = w * 48 + t;
    int m = padv[pp];
    midx_s[t] = m;
    gidx_s[t] = pinv[m];
    canon_s[t] = (unpadv[m] == pp) ? 1 : 0;
    const float* cp = cosb + (size_t)m * 16;
    const float* sp = sinb + (size_t)m * 16;
#pragma unroll
    for (int i = 0; i < 2; i++) {
      *(f32x4*)(cs_s + t * 8 + i * 4) = *(const f32x4*)(cp + i * 4);
      *(f32x4*)(sn_s + t * 8 + i * 4) = *(const f32x4*)(sp + i * 4);
    }
  }
  __syncthreads();

  {  // stage qkv rows with RoPE; V goes in transposed
    const int r = t >> 3, seg = t & 7;
    if (r < 48) {
      const short* rowp = qkv + (size_t)gidx_s[r] * 384;
#pragma unroll
      for (int ci = 0; ci < 3; ci++) {
        const int c0 = seg * 48 + ci * 16;
        const int sec = c0 >> 7;
        const int hh = (c0 & 127) >> 4;
        bf16x8 lo = *(const bf16x8*)(rowp + c0);
        bf16x8 hi = *(const bf16x8*)(rowp + c0 + 8);
        if (sec < 2) {
          bf16x8 w0, w1;
#pragma unroll
          for (int j = 0; j < 8; j++) {
            float x1 = bf2f(lo[j]), x2 = bf2f(hi[j]);
            float cp = cs_s[r * 8 + j], sp2 = sn_s[r * 8 + j];
            w0[j] = f2bf(x1 * cp - x2 * sp2);
            w1[j] = f2bf(x2 * cp + x1 * sp2);
          }
          char* dst = (char*)(sec == 0 ? q_lds : k_lds);
          int sw = (r & 7) << 4;
          *(bf16x8*)(dst + r * 256 + ((hh * 32) ^ sw)) = w0;
          *(bf16x8*)(dst + r * 256 + ((hh * 32 + 16) ^ sw)) = w1;
        } else {
#pragma unroll
          for (int d = 0; d < 16; d++) {
            short val = (d < 8) ? lo[d] : hi[d - 8];
            *(short*)((char*)vT + hh * 2048 + d * 128 + ((r * 2) ^ ((d & 7) << 3))) = val;
          }
        }
      }
    } else {  // r in 48..63: zero the V j-padding
#pragma unroll
      for (int ci = 0; ci < 3; ci++) {
        const int c0 = seg * 48 + ci * 16;
        if (c0 >= 256) {
          const int hh = (c0 & 127) >> 4;
#pragma unroll
          for (int d = 0; d < 16; d++)
            *(short*)((char*)vT + hh * 2048 + d * 128 + ((r * 2) ^ ((d & 7) << 3))) = 0;
        }
      }
    }
  }
  __syncthreads();

  const int h = t >> 6, lane = t & 63, u = lane & 15, g = lane >> 4;
  const int sbase = h * 32 + g * 16;
  bf16x8 zf = {0, 0, 0, 0, 0, 0, 0, 0};
  bf16x8 kf[3], qf[3];
#pragma unroll
  for (int i = 0; i < 3; i++) {
    int kj = i * 16 + u;
    if (g < 2) {
      kf[i] = *(const bf16x8*)((char*)k_lds + kj * 256 + (sbase ^ ((kj & 7) << 4)));
      qf[i] = *(const bf16x8*)((char*)q_lds + kj * 256 + (sbase ^ ((kj & 7) << 4)));
    } else { kf[i] = zf; qf[i] = zf; }
  }
  f32x4 d1[3][3];
#pragma unroll
  for (int a = 0; a < 3; a++)
#pragma unroll
    for (int b = 0; b < 3; b++) {
      f32x4 z = {0.f, 0.f, 0.f, 0.f};
      d1[a][b] = MFMA(kf[a], qf[b], z);  // D1[kj][q] (scores^T)
    }

  float rl[3];
#pragma unroll
  for (int qt = 0; qt < 3; qt++) {
    float mx = -3.0e38f;
#pragma unroll
    for (int kt = 0; kt < 3; kt++)
#pragma unroll
      for (int rr = 0; rr < 4; rr++) {
        float sv = d1[kt][qt][rr] * 0.25f;
        d1[kt][qt][rr] = sv;
        mx = fmaxf(mx, sv);
      }
    mx = fmaxf(mx, __shfl_xor(mx, 16));
    mx = fmaxf(mx, __shfl_xor(mx, 32));
    float sm = 0.f;
#pragma unroll
    for (int kt = 0; kt < 3; kt++)
#pragma unroll
      for (int rr = 0; rr < 4; rr++) {
        float e = __expf(d1[kt][qt][rr] - mx);
        d1[kt][qt][rr] = e;
        sm += e;
      }
    sm += __shfl_xor(sm, 16);
    sm += __shfl_xor(sm, 32);
    rl[qt] = 1.0f / sm;
  }

  union UU { bf16x8 v8; bf16x4 v4[2]; };
  UU a1, a2;
  {
    const int dbase = h * 2048 + u * 128;
    const int sw = (u & 7) << 3;
    a1.v4[0] = *(const bf16x4*)((char*)vT + dbase + ((8 * g) ^ sw));
    a1.v4[1] = *(const bf16x4*)((char*)vT + dbase + ((32 + 8 * g) ^ sw));
    a2.v4[0] = *(const bf16x4*)((char*)vT + dbase + ((64 + 8 * g) ^ sw));
    a2.v4[1] = *(const bf16x4*)((char*)vT + dbase + ((96 + 8 * g) ^ sw));
  }
#pragma unroll
  for (int qt = 0; qt < 3; qt++) {
    UU bu1, bu2;
#pragma unroll
    for (int i = 0; i < 4; i++) {
      bu1.v8[i] = f2bf(d1[0][qt][i]);
      bu1.v8[i + 4] = f2bf(d1[1][qt][i]);
      bu2.v8[i] = f2bf(d1[2][qt][i]);
      bu2.v8[i + 4] = 0;
    }
    f32x4 z = {0.f, 0.f, 0.f, 0.f};
    f32x4 acc = MFMA(a1.v8, bu1.v8, z);
    acc = MFMA(a2.v8, bu2.v8, acc);  // o^T[d][q]
#pragma unroll
    for (int reg = 0; reg < 4; reg++)
      o_lds[(qt * 16 + u) * 128 + h * 16 + 4 * g + reg] = f2bf(acc[reg] * rl[qt]);
  }
  __syncthreads();
  for (int idx = t; idx < 768; idx += 512) {
    int r = idx >> 4, c8 = idx & 15;
    if (canon_s[r]) {
      *(bf16x8*)(ocmp + (size_t)midx_s[r] * 128 + c8 * 8) =
          *(const bf16x8*)(o_lds + r * 128 + c8 * 8);
    }
  }
}

// --------------------- K3: proj GEMM + atomic segment-sum ------------------
__global__ __launch_bounds__(256) void k3_proj(
    const short* __restrict__ ocmp, const short* __restrict__ wp,
    const float* __restrict__ pb, const int* __restrict__ pinv,
    float* __restrict__ dout, int M) {
  __shared__ short a_lds[64 * 128];
  __shared__ int nidx[64];
  const int blk = blockIdx.x, t = threadIdx.x;
  const int m0 = blk * 64;
  {
    const int r = t >> 2, quad = t & 3;
    const int m = m0 + r;
    if (quad == 0) nidx[r] = (m < M) ? pinv[m] : 0;
    if (m < M) {
      const char* src = (const char*)(ocmp + (size_t)m * 128);
#pragma unroll
      for (int i = 0; i < 4; i++) {
        int boff = quad * 64 + i * 16;
        *(bf16x8*)((char*)a_lds + r * 256 + (boff ^ ((r & 7) << 4))) =
            *(const bf16x8*)(src + boff);
      }
    } else {
      bf16x8 z = {0, 0, 0, 0, 0, 0, 0, 0};
#pragma unroll
      for (int i = 0; i < 4; i++) {
        int boff = quad * 64 + i * 16;
        *(bf16x8*)((char*)a_lds + r * 256 + (boff ^ ((r & 7) << 4))) = z;
      }
    }
  }
  __syncthreads();
  const int wave = t >> 6, lane = t & 63, u = lane & 15, g = lane >> 4;
  f32x4 acc[4][2];
  f32x4 zz = {0.f, 0.f, 0.f, 0.f};
#pragma unroll
  for (int a = 0; a < 4; a++) { acc[a][0] = zz; acc[a][1] = zz; }
#pragma unroll
  for (int kk = 0; kk < 4; kk++) {
    bf16x8 af[4];
#pragma unroll
    for (int rt = 0; rt < 4; rt++)
      af[rt] = *(const bf16x8*)((char*)a_lds + (rt * 16 + u) * 256 +
                                ((kk * 64 + g * 16) ^ ((u & 7) << 4)));
    bf16x8 bfr[2];
#pragma unroll
    for (int ct = 0; ct < 2; ct++) {
      int col = wave * 32 + ct * 16 + u;
      bfr[ct] = *(const bf16x8*)(wp + (size_t)col * 128 + kk * 32 + g * 8);
    }
#pragma unroll
    for (int rt = 0; rt < 4; rt++)
#pragma unroll
      for (int ct = 0; ct < 2; ct++) acc[rt][ct] = MFMA(af[rt], bfr[ct], acc[rt][ct]);
  }
#pragma unroll
  for (int rt = 0; rt < 4; rt++)
#pragma unroll
    for (int ct = 0; ct < 2; ct++) {
      int col = wave * 32 + ct * 16 + u;
      float bias = pb[col];
#pragma unroll
      for (int reg = 0; reg < 4; reg++) {
        int ml = rt * 16 + 4 * g + reg;
        if (m0 + ml < M)
          atomicAdd(dout + (size_t)nidx[ml] * 128 + col, acc[rt][ct][reg] + bias);
      }
    }
}

// ------- K4b: x = feat + sums/cnt (in-place in d_out); LN2; fc1+GELU -------
__global__ __launch_bounds__(256) void k4b_x_ln_fc1(
    const float* __restrict__ feat, float* __restrict__ dout,
    const float* __restrict__ cnt, const float* __restrict__ g2,
    const float* __restrict__ b2, const short* __restrict__ w1,
    const float* __restrict__ bb1, short* __restrict__ mact) {
  __shared__ short h_lds[64 * 128];
  __shared__ short o_st[64 * 512];
  const int blk = blockIdx.x, t = threadIdx.x;
  {
    const int r = t >> 2, quad = t & 3;
    const size_t row = (size_t)blk * 64 + r;
    const float* fp = feat + row * 128 + quad * 32;
    float* xp = dout + row * 128 + quad * 32;
    float rc = 1.0f / fmaxf(cnt[row], 1.0f);
    float vals[32];
    float s = 0.f, s2 = 0.f;
#pragma unroll
    for (int i = 0; i < 8; i++) {
      f32x4 fv = *(const f32x4*)(fp + i * 4);
      f32x4 sv = *(const f32x4*)(xp + i * 4);
      f32x4 xv;
#pragma unroll
      for (int j = 0; j < 4; j++) {
        float x = fv[j] + sv[j] * rc;
        xv[j] = x; vals[i * 4 + j] = x; s += x; s2 += x * x;
      }
      *(f32x4*)(xp + i * 4) = xv;
    }
    s += __shfl_xor(s, 1);  s += __shfl_xor(s, 2);
    s2 += __shfl_xor(s2, 1); s2 += __shfl_xor(s2, 2);
    float mean = s * (1.f / 128.f);
    float rstd = rsqrtf(s2 * (1.f / 128.f) - mean * mean + 1e-5f);
    const int sw = (r & 7) << 4;
#pragma unroll
    for (int gi = 0; gi < 4; gi++) {
      bf16x8 wv;
#pragma unroll
      for (int j = 0; j < 8; j++) {
        int c = quad * 32 + gi * 8 + j;
        wv[j] = f2bf((vals[gi * 8 + j] - mean) * rstd * g2[c] + b2[c]);
      }
      *(bf16x8*)((char*)h_lds + r * 256 + ((quad * 64 + gi * 16) ^ sw)) = wv;
    }
  }
  __syncthreads();
  const int wave = t >> 6, lane = t & 63, u = lane & 15, g = lane >> 4;
  f32x4 acc[4][8];
  f32x4 zz = {0.f, 0.f, 0.f, 0.f};
#pragma unroll
  for (int a = 0; a < 4; a++)
#pragma unroll
    for (int b = 0; b < 8; b++) acc[a][b] = zz;
#pragma unroll
  for (int kk = 0; kk < 4; kk++) {
    bf16x8 af[4];
#pragma unroll
    for (int rt = 0; rt < 4; rt++)
      af[rt] = *(const bf16x8*)((char*)h_lds + (rt * 16 + u) * 256 +
                                ((kk * 64 + g * 16) ^ ((u & 7) << 4)));
    bf16x8 bfr[8];
#pragma unroll
    for (int ct = 0; ct < 8; ct++) {
      int col = wave * 128 + ct * 16 + u;
      bfr[ct] = *(const bf16x8*)(w1 + (size_t)col * 128 + kk * 32 + g * 8);
    }
#pragma unroll
    for (int rt = 0; rt < 4; rt++)
#pragma unroll
      for (int ct = 0; ct < 8; ct++) acc[rt][ct] = MFMA(af[rt], bfr[ct], acc[rt][ct]);
  }
#pragma unroll
  for (int rt = 0; rt < 4; rt++)
#pragma unroll
    for (int ct = 0; ct < 8; ct++) {
      int col = wave * 128 + ct * 16 + u;
      float bias = bb1[col];
#pragma unroll
      for (int reg = 0; reg < 4; reg++) {
        int rowl = rt * 16 + 4 * g + reg;
        float v = acc[rt][ct][reg] + bias;
        v = 0.5f * v * (1.0f + erff(v * 0.70710678118654752f));  // exact GELU
        o_st[rowl * 512 + col] = f2bf(v);
      }
    }
  __syncthreads();
  for (int idx = t; idx < 4096; idx += 256) {
    int rr = idx >> 6, c8 = idx & 63;
    *(bf16x8*)(mact + ((size_t)blk * 64 + rr) * 512 + c8 * 8) =
        *(const bf16x8*)(o_st + rr * 512 + c8 * 8);
  }
}

// --------------------- K4c: fc2 + residual into d_out ----------------------
__global__ __launch_bounds__(256) void k4c_fc2(
    const short* __restrict__ mact, const short* __restrict__ w2,
    const float* __restrict__ bb2, float* __restrict__ dout) {
  __shared__ short a_lds[64 * 512];
  const int blk = blockIdx.x, t = threadIdx.x;
  {
    const int r = t >> 2, quad = t & 3;
    const size_t row = (size_t)blk * 64 + r;
    const char* src = (const char*)(mact + row * 512);
#pragma unroll
    for (int i = 0; i < 16; i++) {
      int boff = quad * 256 + i * 16;
      *(bf16x8*)((char*)a_lds + r * 1024 + (boff ^ ((r & 7) << 4))) =
          *(const bf16x8*)(src + boff);
    }
  }
  __syncthreads();
  const int wave = t >> 6, lane = t & 63, u = lane & 15, g = lane >> 4;
  f32x4 acc[8];
  f32x4 zz = {0.f, 0.f, 0.f, 0.f};
#pragma unroll
  for (int a = 0; a < 8; a++) acc[a] = zz;
  const int rowl = wave * 16 + u;
#pragma unroll
  for (int kk = 0; kk < 16; kk++) {
    bf16x8 af = *(const bf16x8*)((char*)a_lds + rowl * 1024 +
                                 ((kk * 64 + g * 16) ^ ((u & 7) << 4)));
#pragma unroll
    for (int ct = 0; ct < 8; ct++) {
      int col = ct * 16 + u;
      bf16x8 bfr = *(const bf16x8*)(w2 + (size_t)col * 512 + kk * 32 + g * 8);
      acc[ct] = MFMA(af, bfr, acc[ct]);
    }
  }
#pragma unroll
  for (int ct = 0; ct < 8; ct++) {
    int col = ct * 16 + u;
    float bias = bb2[col];
#pragma unroll
    for (int reg = 0; reg < 4; reg++) {
      size_t rr = (size_t)blk * 64 + wave * 16 + 4 * g + reg;
      float* p = dout + rr * 128 + col;
      *p = *p + acc[ct][reg] + bias;
    }
  }
}

// ---------------------------------------------------------------------------
extern "C" void kernel_launch(void* const* d_in, const int* in_sizes, int n_in,
                              void* d_out, int out_size, void* d_ws, size_t ws_size,
                              hipStream_t stream) {
  (void)n_in; (void)out_size; (void)ws_size;
  const float* feat   = (const float*)d_in[0];
  const float* cosb   = (const float*)d_in[1];
  const float* sinb   = (const float*)d_in[2];
  const float* g1     = (const float*)d_in[3];
  const float* b1     = (const float*)d_in[4];
  const float* qkv_w  = (const float*)d_in[5];
  const float* qkv_b  = (const float*)d_in[6];
  const float* proj_w = (const float*)d_in[7];
  const float* proj_b = (const float*)d_in[8];
  const float* g2     = (const float*)d_in[9];
  const float* b2     = (const float*)d_in[10];
  const float* fc1_w  = (const float*)d_in[11];
  const float* fc1_b  = (const float*)d_in[12];
  const float* fc2_w  = (const float*)d_in[13];
  const float* fc2_b  = (const float*)d_in[14];
  const int* pinv     = (const int*)d_in[15];
  const int* padv     = (const int*)d_in[16];
  const int* unpadv   = (const int*)d_in[17];

  const int N    = in_sizes[0] / 128;
  const int M    = in_sizes[15];
  const int Mpad = in_sizes[16];
  const int Wn   = Mpad / 48;

  float* dout = (float*)d_out;
  char* ws = (char*)d_ws;

  // ws layout (bytes):
  //  [0, N*384*2)                      qkv bf16        (dead after K2)
  //  [N*384*2, +M*128*2)               o_cmp bf16      (dead after K3)
  //  [0, N*512*2)                      mact bf16       (reuses qkv+ocmp space)
  //  then cnt (N*4), then bf16 weights (393216 B). Total ~175 MB.
  size_t offQ = 0;
  size_t szQ = (size_t)N * 384 * 2;
  size_t offO = offQ + szQ;
  size_t szO = (size_t)M * 128 * 2;
  size_t offC = offO + szO;
  size_t offW = offC + (size_t)N * 4;

  short* qkvb = (short*)(ws + offQ);
  short* ocmp = (short*)(ws + offO);
  short* mact = (short*)(ws + offQ);  // overlaps qkv/ocmp (both dead by K4b)
  float* cnt  = (float*)(ws + offC);
  short* wq_b = (short*)(ws + offW);
  short* wp_b = wq_b + 49152;
  short* w1_b = wp_b + 16384;
  short* w2_b = w1_b + 65536;

  hipMemsetAsync(dout, 0, (size_t)N * 128 * 4, stream);
  hipMemsetAsync(cnt, 0, (size_t)N * 4, stream);

  k_cvt<<<(49152 + 255) / 256, 256, 0, stream>>>(qkv_w, wq_b, 49152);
  k_cvt<<<(16384 + 255) / 256, 256, 0, stream>>>(proj_w, wp_b, 16384);
  k_cvt<<<(65536 + 255) / 256, 256, 0, stream>>>(fc1_w, w1_b, 65536);
  k_cvt<<<(65536 + 255) / 256, 256, 0, stream>>>(fc2_w, w2_b, 65536);

  k1_ln_qkv<<<N / 64, 256, 0, stream>>>(feat, g1, b1, wq_b, qkv_b, qkvb);
  k_cnt<<<(M + 255) / 256, 256, 0, stream>>>(pinv, cnt, M);
  k2_attn<<<Wn, 512, 0, stream>>>(qkvb, cosb, sinb, pinv, padv, unpadv, ocmp);
  k3_proj<<<(M + 63) / 64, 256, 0, stream>>>(ocmp, wp_b, proj_b, pinv, dout, M);
  k4b_x_ln_fc1<<<N / 64, 256, 0, stream>>>(feat, dout, cnt, g2, b2, w1_b, fc1_b, mact);
  k4c_fc2<<<N / 64, 256, 0, stream>>>(mact, w2_b, fc2_b, dout);
}

// Round 4
// 636.673 us; speedup vs baseline: 1.1240x; 1.1240x over previous
//
#include <hip/hip_runtime.h>

// ---------------------------------------------------------------------------
// PathAttention block on MI355X. bf16 MFMA for all GEMM-shaped work.
// Round 4: occupancy pass — shrink/eliminate LDS staging everywhere.
// Needs ~175 MB of d_ws.
// ---------------------------------------------------------------------------

typedef __attribute__((ext_vector_type(4))) float f32x4;
typedef __attribute__((ext_vector_type(8))) short bf16x8;
typedef __attribute__((ext_vector_type(4))) short bf16x4;

#define MFMA(a, b, c) __builtin_amdgcn_mfma_f32_16x16x32_bf16(a, b, c, 0, 0, 0)

static __device__ __forceinline__ short f2bf(float x) {
  union { float f; unsigned u; } v; v.f = x;
  unsigned r = v.u + 0x7FFFu + ((v.u >> 16) & 1u);
  return (short)(r >> 16);
}
static __device__ __forceinline__ float bf2f(short b) {
  union { unsigned u; float f; } v;
  v.u = ((unsigned)(unsigned short)b) << 16;
  return v.f;
}

// ------------------------------ weight convert -----------------------------
__global__ void k_cvt(const float* __restrict__ s, short* __restrict__ d, int n) {
  int i = blockIdx.x * 256 + threadIdx.x;
  if (i < n) d[i] = f2bf(s[i]);
}

// ------------------------------ cnt histogram ------------------------------
__global__ void k_cnt(const int* __restrict__ pinv, float* __restrict__ cnt, int M) {
  int i = blockIdx.x * 256 + threadIdx.x;
  if (i < M) atomicAdd(&cnt[pinv[i]], 1.0f);
}

// --------------------- K1: LN(feat) -> qkv GEMM (bf16 out) -----------------
// 32-row tile, 256 thr. LDS = 8 KB h + 24 KB out stage = 32 KB.
__global__ __launch_bounds__(256) void k1_ln_qkv(
    const float* __restrict__ feat, const float* __restrict__ g1,
    const float* __restrict__ b1, const short* __restrict__ wq,
    const float* __restrict__ bq, short* __restrict__ qkvb) {
  __shared__ short h_lds[32 * 128];
  __shared__ short o_st[32 * 384];
  const int blk = blockIdx.x, t = threadIdx.x;
  {
    const int r = t >> 3, oct = t & 7;
    const float* fp = feat + (size_t)(blk * 32 + r) * 128 + oct * 16;
    float vals[16];
    float s = 0.f, s2 = 0.f;
#pragma unroll
    for (int i = 0; i < 4; i++) {
      f32x4 v = *(const f32x4*)(fp + i * 4);
#pragma unroll
      for (int j = 0; j < 4; j++) { float x = v[j]; vals[i * 4 + j] = x; s += x; s2 += x * x; }
    }
    s += __shfl_xor(s, 1);  s += __shfl_xor(s, 2);  s += __shfl_xor(s, 4);
    s2 += __shfl_xor(s2, 1); s2 += __shfl_xor(s2, 2); s2 += __shfl_xor(s2, 4);
    float mean = s * (1.f / 128.f);
    float rstd = rsqrtf(s2 * (1.f / 128.f) - mean * mean + 1e-5f);
    const int sw = (r & 7) << 4;
#pragma unroll
    for (int gi = 0; gi < 2; gi++) {
      bf16x8 wv;
#pragma unroll
      for (int j = 0; j < 8; j++) {
        int c = oct * 16 + gi * 8 + j;
        wv[j] = f2bf((vals[gi * 8 + j] - mean) * rstd * g1[c] + b1[c]);
      }
      *(bf16x8*)((char*)h_lds + r * 256 + ((oct * 32 + gi * 16) ^ sw)) = wv;
    }
  }
  __syncthreads();
  const int wave = t >> 6, lane = t & 63, u = lane & 15, g = lane >> 4;
  f32x4 acc[2][6];
  f32x4 zz = {0.f, 0.f, 0.f, 0.f};
#pragma unroll
  for (int a = 0; a < 2; a++)
#pragma unroll
    for (int b = 0; b < 6; b++) acc[a][b] = zz;
#pragma unroll
  for (int kk = 0; kk < 4; kk++) {
    bf16x8 af[2];
#pragma unroll
    for (int rt = 0; rt < 2; rt++)
      af[rt] = *(const bf16x8*)((char*)h_lds + (rt * 16 + u) * 256 +
                                ((kk * 64 + g * 16) ^ ((u & 7) << 4)));
    bf16x8 bfr[6];
#pragma unroll
    for (int ct = 0; ct < 6; ct++) {
      int col = wave * 96 + ct * 16 + u;
      bfr[ct] = *(const bf16x8*)(wq + (size_t)col * 128 + kk * 32 + g * 8);
    }
#pragma unroll
    for (int rt = 0; rt < 2; rt++)
#pragma unroll
      for (int ct = 0; ct < 6; ct++) acc[rt][ct] = MFMA(af[rt], bfr[ct], acc[rt][ct]);
  }
  // stage to LDS, swizzled so each scalar-store inst spans 32 banks
#pragma unroll
  for (int rt = 0; rt < 2; rt++)
#pragma unroll
    for (int ct = 0; ct < 6; ct++) {
      int col = wave * 96 + ct * 16 + u;
      float bias = bq[col];
#pragma unroll
      for (int reg = 0; reg < 4; reg++) {
        int rowl = rt * 16 + 4 * g + reg;
        *(short*)((char*)o_st + rowl * 768 + ((col * 2) ^ (g << 5))) =
            f2bf(acc[rt][ct][reg] + bias);
      }
    }
  __syncthreads();
  for (int idx = t; idx < 1536; idx += 256) {
    int r = idx / 48, c8 = idx % 48;
    bf16x8 v = *(const bf16x8*)((char*)o_st + r * 768 +
                                ((c8 * 16) ^ ((((r >> 2) & 3)) << 5)));
    *(bf16x8*)(qkvb + ((size_t)blk * 32 + r) * 384 + c8 * 8) = v;
  }
}

// --------------------- K2: windowed attention per 48-block -----------------
// 512 thr (8 waves = 8 heads). Output tile aliases the Q buffer (dead after
// fragment loads) with a 272 B padded row stride. LDS ~45 KB.
__global__ __launch_bounds__(512) void k2_attn(
    const short* __restrict__ qkv, const float* __restrict__ cosb,
    const float* __restrict__ sinb, const int* __restrict__ pinv,
    const int* __restrict__ padv, const int* __restrict__ unpadv,
    short* __restrict__ ocmp) {
  __shared__ short qo_lds[48 * 136];  // q: 256 B row stride; o: 272 B stride
  __shared__ short k_lds[48 * 128];
  __shared__ short vT[8 * 16 * 64];   // [h][d][j], j padded to 64
  __shared__ int midx_s[48];
  __shared__ int gidx_s[48];
  __shared__ int canon_s[48];
  __shared__ float cs_s[48 * 8];
  __shared__ float sn_s[48 * 8];

  const int w = blockIdx.x;
  const int t = threadIdx.x;

  if (t < 48) {
    int pp = w * 48 + t;
    int m = padv[pp];
    midx_s[t] = m;
    gidx_s[t] = pinv[m];
    canon_s[t] = (unpadv[m] == pp) ? 1 : 0;
    const float* cp = cosb + (size_t)m * 16;
    const float* sp = sinb + (size_t)m * 16;
#pragma unroll
    for (int i = 0; i < 2; i++) {
      *(f32x4*)(cs_s + t * 8 + i * 4) = *(const f32x4*)(cp + i * 4);
      *(f32x4*)(sn_s + t * 8 + i * 4) = *(const f32x4*)(sp + i * 4);
    }
  }
  __syncthreads();

  {  // stage qkv rows with RoPE; V goes in transposed
    const int r = t >> 3, seg = t & 7;
    if (r < 48) {
      const short* rowp = qkv + (size_t)gidx_s[r] * 384;
#pragma unroll
      for (int ci = 0; ci < 3; ci++) {
        const int c0 = seg * 48 + ci * 16;
        const int sec = c0 >> 7;
        const int hh = (c0 & 127) >> 4;
        bf16x8 lo = *(const bf16x8*)(rowp + c0);
        bf16x8 hi = *(const bf16x8*)(rowp + c0 + 8);
        if (sec < 2) {
          bf16x8 w0, w1;
#pragma unroll
          for (int j = 0; j < 8; j++) {
            float x1 = bf2f(lo[j]), x2 = bf2f(hi[j]);
            float cp = cs_s[r * 8 + j], sp2 = sn_s[r * 8 + j];
            w0[j] = f2bf(x1 * cp - x2 * sp2);
            w1[j] = f2bf(x2 * cp + x1 * sp2);
          }
          char* dst = (char*)(sec == 0 ? qo_lds : k_lds);
          int sw = (r & 7) << 4;
          *(bf16x8*)(dst + r * 256 + ((hh * 32) ^ sw)) = w0;
          *(bf16x8*)(dst + r * 256 + ((hh * 32 + 16) ^ sw)) = w1;
        } else {
#pragma unroll
          for (int d = 0; d < 16; d++) {
            short val = (d < 8) ? lo[d] : hi[d - 8];
            *(short*)((char*)vT + hh * 2048 + d * 128 + ((r * 2) ^ ((d & 7) << 3))) = val;
          }
        }
      }
    } else {  // r in 48..63: zero the V j-padding
#pragma unroll
      for (int ci = 0; ci < 3; ci++) {
        const int c0 = seg * 48 + ci * 16;
        if (c0 >= 256) {
          const int hh = (c0 & 127) >> 4;
#pragma unroll
          for (int d = 0; d < 16; d++)
            *(short*)((char*)vT + hh * 2048 + d * 128 + ((r * 2) ^ ((d & 7) << 3))) = 0;
        }
      }
    }
  }
  __syncthreads();

  const int h = t >> 6, lane = t & 63, u = lane & 15, g = lane >> 4;
  const int sbase = h * 32 + g * 16;
  bf16x8 zf = {0, 0, 0, 0, 0, 0, 0, 0};
  bf16x8 kf[3], qf[3];
#pragma unroll
  for (int i = 0; i < 3; i++) {
    int kj = i * 16 + u;
    if (g < 2) {
      kf[i] = *(const bf16x8*)((char*)k_lds + kj * 256 + (sbase ^ ((kj & 7) << 4)));
      qf[i] = *(const bf16x8*)((char*)qo_lds + kj * 256 + (sbase ^ ((kj & 7) << 4)));
    } else { kf[i] = zf; qf[i] = zf; }
  }
  union UU { bf16x8 v8; bf16x4 v4[2]; };
  UU a1, a2;
  {
    const int dbase = h * 2048 + u * 128;
    const int sw = (u & 7) << 3;
    a1.v4[0] = *(const bf16x4*)((char*)vT + dbase + ((8 * g) ^ sw));
    a1.v4[1] = *(const bf16x4*)((char*)vT + dbase + ((32 + 8 * g) ^ sw));
    a2.v4[0] = *(const bf16x4*)((char*)vT + dbase + ((64 + 8 * g) ^ sw));
    a2.v4[1] = *(const bf16x4*)((char*)vT + dbase + ((96 + 8 * g) ^ sw));
  }
  __syncthreads();  // all LDS reads done; qo_lds may now be overwritten

  f32x4 d1[3][3];
#pragma unroll
  for (int a = 0; a < 3; a++)
#pragma unroll
    for (int b = 0; b < 3; b++) {
      f32x4 z = {0.f, 0.f, 0.f, 0.f};
      d1[a][b] = MFMA(kf[a], qf[b], z);  // D1[kj][q] (scores^T)
    }

  float rl[3];
#pragma unroll
  for (int qt = 0; qt < 3; qt++) {
    float mx = -3.0e38f;
#pragma unroll
    for (int kt = 0; kt < 3; kt++)
#pragma unroll
      for (int rr = 0; rr < 4; rr++) {
        float sv = d1[kt][qt][rr] * 0.25f;
        d1[kt][qt][rr] = sv;
        mx = fmaxf(mx, sv);
      }
    mx = fmaxf(mx, __shfl_xor(mx, 16));
    mx = fmaxf(mx, __shfl_xor(mx, 32));
    float sm = 0.f;
#pragma unroll
    for (int kt = 0; kt < 3; kt++)
#pragma unroll
      for (int rr = 0; rr < 4; rr++) {
        float e = __expf(d1[kt][qt][rr] - mx);
        d1[kt][qt][rr] = e;
        sm += e;
      }
    sm += __shfl_xor(sm, 16);
    sm += __shfl_xor(sm, 32);
    rl[qt] = 1.0f / sm;
  }

#pragma unroll
  for (int qt = 0; qt < 3; qt++) {
    UU bu1, bu2;
#pragma unroll
    for (int i = 0; i < 4; i++) {
      bu1.v8[i] = f2bf(d1[0][qt][i]);
      bu1.v8[i + 4] = f2bf(d1[1][qt][i]);
      bu2.v8[i] = f2bf(d1[2][qt][i]);
      bu2.v8[i + 4] = 0;
    }
    f32x4 z = {0.f, 0.f, 0.f, 0.f};
    f32x4 acc = MFMA(a1.v8, bu1.v8, z);
    acc = MFMA(a2.v8, bu2.v8, acc);  // o^T[d][q]
#pragma unroll
    for (int reg = 0; reg < 4; reg++)
      *(short*)((char*)qo_lds + (qt * 16 + u) * 272 + h * 32 + g * 8 + reg * 2) =
          f2bf(acc[reg] * rl[qt]);
  }
  __syncthreads();
  for (int idx = t; idx < 768; idx += 512) {
    int r = idx >> 4, c8 = idx & 15;
    if (canon_s[r]) {
      *(bf16x8*)(ocmp + (size_t)midx_s[r] * 128 + c8 * 8) =
          *(const bf16x8*)((char*)qo_lds + r * 272 + c8 * 16);
    }
  }
}

// --------------------- K3: proj GEMM + atomic segment-sum ------------------
// A-fragments loaded straight from global (contiguous 16 B per lane). LDS=256B.
__global__ __launch_bounds__(256) void k3_proj(
    const short* __restrict__ ocmp, const short* __restrict__ wp,
    const float* __restrict__ pb, const int* __restrict__ pinv,
    float* __restrict__ dout, int M) {
  __shared__ int nidx[64];
  const int blk = blockIdx.x, t = threadIdx.x;
  const int m0 = blk * 64;
  if (t < 64) nidx[t] = (m0 + t < M) ? pinv[m0 + t] : 0;
  __syncthreads();
  const int wave = t >> 6, lane = t & 63, u = lane & 15, g = lane >> 4;
  f32x4 acc[4][2];
  f32x4 zz = {0.f, 0.f, 0.f, 0.f};
#pragma unroll
  for (int a = 0; a < 4; a++) { acc[a][0] = zz; acc[a][1] = zz; }
  bf16x8 zf = {0, 0, 0, 0, 0, 0, 0, 0};
#pragma unroll
  for (int kk = 0; kk < 4; kk++) {
    bf16x8 af[4];
#pragma unroll
    for (int rt = 0; rt < 4; rt++) {
      int m = m0 + rt * 16 + u;
      af[rt] = (m < M) ? *(const bf16x8*)(ocmp + (size_t)m * 128 + kk * 32 + g * 8) : zf;
    }
    bf16x8 bfr[2];
#pragma unroll
    for (int ct = 0; ct < 2; ct++) {
      int col = wave * 32 + ct * 16 + u;
      bfr[ct] = *(const bf16x8*)(wp + (size_t)col * 128 + kk * 32 + g * 8);
    }
#pragma unroll
    for (int rt = 0; rt < 4; rt++)
#pragma unroll
      for (int ct = 0; ct < 2; ct++) acc[rt][ct] = MFMA(af[rt], bfr[ct], acc[rt][ct]);
  }
#pragma unroll
  for (int rt = 0; rt < 4; rt++)
#pragma unroll
    for (int ct = 0; ct < 2; ct++) {
      int col = wave * 32 + ct * 16 + u;
      float bias = pb[col];
#pragma unroll
      for (int reg = 0; reg < 4; reg++) {
        int ml = rt * 16 + 4 * g + reg;
        if (m0 + ml < M)
          atomicAdd(dout + (size_t)nidx[ml] * 128 + col, acc[rt][ct][reg] + bias);
      }
    }
}

// ------- K4b: x = feat + sums/cnt (in-place in d_out); LN2; fc1+GELU -------
// 32-row tile; per-rt 16x512 swizzled stage. LDS = 8 + 16 = 24 KB.
__global__ __launch_bounds__(256) void k4b_x_ln_fc1(
    const float* __restrict__ feat, float* __restrict__ dout,
    const float* __restrict__ cnt, const float* __restrict__ g2,
    const float* __restrict__ b2, const short* __restrict__ w1,
    const float* __restrict__ bb1, short* __restrict__ mact) {
  __shared__ short h_lds[32 * 128];
  __shared__ short o_st[16 * 512];
  const int blk = blockIdx.x, t = threadIdx.x;
  {
    const int r = t >> 3, oct = t & 7;
    const size_t row = (size_t)blk * 32 + r;
    const float* fp = feat + row * 128 + oct * 16;
    float* xp = dout + row * 128 + oct * 16;
    float rc = 1.0f / fmaxf(cnt[row], 1.0f);
    float vals[16];
    float s = 0.f, s2 = 0.f;
#pragma unroll
    for (int i = 0; i < 4; i++) {
      f32x4 fv = *(const f32x4*)(fp + i * 4);
      f32x4 sv = *(const f32x4*)(xp + i * 4);
      f32x4 xv;
#pragma unroll
      for (int j = 0; j < 4; j++) {
        float x = fv[j] + sv[j] * rc;
        xv[j] = x; vals[i * 4 + j] = x; s += x; s2 += x * x;
      }
      *(f32x4*)(xp + i * 4) = xv;
    }
    s += __shfl_xor(s, 1);  s += __shfl_xor(s, 2);  s += __shfl_xor(s, 4);
    s2 += __shfl_xor(s2, 1); s2 += __shfl_xor(s2, 2); s2 += __shfl_xor(s2, 4);
    float mean = s * (1.f / 128.f);
    float rstd = rsqrtf(s2 * (1.f / 128.f) - mean * mean + 1e-5f);
    const int sw = (r & 7) << 4;
#pragma unroll
    for (int gi = 0; gi < 2; gi++) {
      bf16x8 wv;
#pragma unroll
      for (int j = 0; j < 8; j++) {
        int c = oct * 16 + gi * 8 + j;
        wv[j] = f2bf((vals[gi * 8 + j] - mean) * rstd * g2[c] + b2[c]);
      }
      *(bf16x8*)((char*)h_lds + r * 256 + ((oct * 32 + gi * 16) ^ sw)) = wv;
    }
  }
  __syncthreads();
  const int wave = t >> 6, lane = t & 63, u = lane & 15, g = lane >> 4;
  f32x4 acc[2][8];
  f32x4 zz = {0.f, 0.f, 0.f, 0.f};
#pragma unroll
  for (int a = 0; a < 2; a++)
#pragma unroll
    for (int b = 0; b < 8; b++) acc[a][b] = zz;
#pragma unroll
  for (int kk = 0; kk < 4; kk++) {
    bf16x8 af[2];
#pragma unroll
    for (int rt = 0; rt < 2; rt++)
      af[rt] = *(const bf16x8*)((char*)h_lds + (rt * 16 + u) * 256 +
                                ((kk * 64 + g * 16) ^ ((u & 7) << 4)));
    bf16x8 bfr[8];
#pragma unroll
    for (int ct = 0; ct < 8; ct++) {
      int col = wave * 128 + ct * 16 + u;
      bfr[ct] = *(const bf16x8*)(w1 + (size_t)col * 128 + kk * 32 + g * 8);
    }
#pragma unroll
    for (int rt = 0; rt < 2; rt++)
#pragma unroll
      for (int ct = 0; ct < 8; ct++) acc[rt][ct] = MFMA(af[rt], bfr[ct], acc[rt][ct]);
  }
  // per-rt: GELU -> swizzled stage -> coalesced global store
  for (int rt = 0; rt < 2; rt++) {
#pragma unroll
    for (int ct = 0; ct < 8; ct++) {
      int col = wave * 128 + ct * 16 + u;
      float bias = bb1[col];
#pragma unroll
      for (int reg = 0; reg < 4; reg++) {
        int row16 = 4 * g + reg;
        float v = acc[rt][ct][reg] + bias;
        v = 0.5f * v * (1.0f + erff(v * 0.70710678118654752f));  // exact GELU
        *(short*)((char*)o_st + row16 * 1024 + ((col * 2) ^ (g << 5))) = f2bf(v);
      }
    }
    __syncthreads();
    for (int it = 0; it < 4; it++) {
      int idx = t + it * 256;
      int row16 = idx >> 6, c8 = idx & 63;
      bf16x8 v = *(const bf16x8*)((char*)o_st + row16 * 1024 +
                                  ((c8 * 16) ^ (((row16 >> 2) & 3) << 5)));
      *(bf16x8*)(mact + ((size_t)blk * 32 + rt * 16 + row16) * 512 + c8 * 8) = v;
    }
    __syncthreads();
  }
}

// --------------------- K4c: fc2 + residual into d_out ----------------------
// No LDS: A-fragments loaded straight from mact (16 B contiguous per lane).
__global__ __launch_bounds__(256) void k4c_fc2(
    const short* __restrict__ mact, const short* __restrict__ w2,
    const float* __restrict__ bb2, float* __restrict__ dout) {
  const int blk = blockIdx.x, t = threadIdx.x;
  const int wave = t >> 6, lane = t & 63, u = lane & 15, g = lane >> 4;
  const size_t row = (size_t)blk * 64 + wave * 16 + u;
  const short* ap = mact + row * 512;
  f32x4 acc[8];
  f32x4 zz = {0.f, 0.f, 0.f, 0.f};
#pragma unroll
  for (int a = 0; a < 8; a++) acc[a] = zz;
#pragma unroll
  for (int kk = 0; kk < 16; kk++) {
    bf16x8 af = *(const bf16x8*)(ap + kk * 32 + g * 8);
#pragma unroll
    for (int ct = 0; ct < 8; ct++) {
      int col = ct * 16 + u;
      bf16x8 bfr = *(const bf16x8*)(w2 + (size_t)col * 512 + kk * 32 + g * 8);
      acc[ct] = MFMA(af, bfr, acc[ct]);
    }
  }
#pragma unroll
  for (int ct = 0; ct < 8; ct++) {
    int col = ct * 16 + u;
    float bias = bb2[col];
#pragma unroll
    for (int reg = 0; reg < 4; reg++) {
      size_t rr = (size_t)blk * 64 + wave * 16 + 4 * g + reg;
      float* p = dout + rr * 128 + col;
      *p = *p + acc[ct][reg] + bias;
    }
  }
}

// ---------------------------------------------------------------------------
extern "C" void kernel_launch(void* const* d_in, const int* in_sizes, int n_in,
                              void* d_out, int out_size, void* d_ws, size_t ws_size,
                              hipStream_t stream) {
  (void)n_in; (void)out_size; (void)ws_size;
  const float* feat   = (const float*)d_in[0];
  const float* cosb   = (const float*)d_in[1];
  const float* sinb   = (const float*)d_in[2];
  const float* g1     = (const float*)d_in[3];
  const float* b1     = (const float*)d_in[4];
  const float* qkv_w  = (const float*)d_in[5];
  const float* qkv_b  = (const float*)d_in[6];
  const float* proj_w = (const float*)d_in[7];
  const float* proj_b = (const float*)d_in[8];
  const float* g2     = (const float*)d_in[9];
  const float* b2     = (const float*)d_in[10];
  const float* fc1_w  = (const float*)d_in[11];
  const float* fc1_b  = (const float*)d_in[12];
  const float* fc2_w  = (const float*)d_in[13];
  const float* fc2_b  = (const float*)d_in[14];
  const int* pinv     = (const int*)d_in[15];
  const int* padv     = (const int*)d_in[16];
  const int* unpadv   = (const int*)d_in[17];

  const int N    = in_sizes[0] / 128;
  const int M    = in_sizes[15];
  const int Mpad = in_sizes[16];
  const int Wn   = Mpad / 48;

  float* dout = (float*)d_out;
  char* ws = (char*)d_ws;

  // ws layout (bytes):
  //  [0, N*384*2)                      qkv bf16        (dead after K2)
  //  [N*384*2, +M*128*2)               o_cmp bf16      (dead after K3)
  //  [0, N*512*2)                      mact bf16       (reuses qkv+ocmp space)
  //  then cnt (N*4), then bf16 weights (393216 B). Total ~175 MB.
  size_t offQ = 0;
  size_t szQ = (size_t)N * 384 * 2;
  size_t offO = offQ + szQ;
  size_t szO = (size_t)M * 128 * 2;
  size_t offC = offO + szO;
  size_t offW = offC + (size_t)N * 4;

  short* qkvb = (short*)(ws + offQ);
  short* ocmp = (short*)(ws + offO);
  short* mact = (short*)(ws + offQ);  // overlaps qkv/ocmp (both dead by K4b)
  float* cnt  = (float*)(ws + offC);
  short* wq_b = (short*)(ws + offW);
  short* wp_b = wq_b + 49152;
  short* w1_b = wp_b + 16384;
  short* w2_b = w1_b + 65536;

  hipMemsetAsync(dout, 0, (size_t)N * 128 * 4, stream);
  hipMemsetAsync(cnt, 0, (size_t)N * 4, stream);

  k_cvt<<<(49152 + 255) / 256, 256, 0, stream>>>(qkv_w, wq_b, 49152);
  k_cvt<<<(16384 + 255) / 256, 256, 0, stream>>>(proj_w, wp_b, 16384);
  k_cvt<<<(65536 + 255) / 256, 256, 0, stream>>>(fc1_w, w1_b, 65536);
  k_cvt<<<(65536 + 255) / 256, 256, 0, stream>>>(fc2_w, w2_b, 65536);

  k1_ln_qkv<<<N / 32, 256, 0, stream>>>(feat, g1, b1, wq_b, qkv_b, qkvb);
  k_cnt<<<(M + 255) / 256, 256, 0, stream>>>(pinv, cnt, M);
  k2_attn<<<Wn, 512, 0, stream>>>(qkvb, cosb, sinb, pinv, padv, unpadv, ocmp);
  k3_proj<<<(M + 63) / 64, 256, 0, stream>>>(ocmp, wp_b, proj_b, pinv, dout, M);
  k4b_x_ln_fc1<<<N / 32, 256, 0, stream>>>(feat, dout, cnt, g2, b2, w1_b, fc1_b, mact);
  k4c_fc2<<<N / 64, 256, 0, stream>>>(mact, w2_b, fc2_b, dout);
}

// Round 5
// 480.565 us; speedup vs baseline: 1.4891x; 1.3248x over previous
//
#include <hip/hip_runtime.h>

// ---------------------------------------------------------------------------
// PathAttention block on MI355X. bf16 MFMA for all GEMM-shaped work.
// Round 5: kill fp32 scatter-atomics (counting sort + gather); fuse fc1+fc2.
// Peak ws ~175 MB (sort arrays live in the dead qkv-region tail).
// ---------------------------------------------------------------------------

typedef __attribute__((ext_vector_type(4))) float f32x4;
typedef __attribute__((ext_vector_type(8))) short bf16x8;
typedef __attribute__((ext_vector_type(4))) short bf16x4;

#define MFMA(a, b, c) __builtin_amdgcn_mfma_f32_16x16x32_bf16(a, b, c, 0, 0, 0)

static __device__ __forceinline__ short f2bf(float x) {
  union { float f; unsigned u; } v; v.f = x;
  unsigned r = v.u + 0x7FFFu + ((v.u >> 16) & 1u);
  return (short)(r >> 16);
}
static __device__ __forceinline__ float bf2f(short b) {
  union { unsigned u; float f; } v;
  v.u = ((unsigned)(unsigned short)b) << 16;
  return v.f;
}

// ------------------------------ weight convert -----------------------------
__global__ void k_cvt(const float* __restrict__ s, short* __restrict__ d, int n) {
  int i = blockIdx.x * 256 + threadIdx.x;
  if (i < n) d[i] = f2bf(s[i]);
}

// --------------------- counting sort of path_inverse -----------------------
__global__ void k_cnt(const int* __restrict__ pinv, int* __restrict__ cnt, int M) {
  int i = blockIdx.x * 256 + threadIdx.x;
  if (i < M) atomicAdd(&cnt[pinv[i]], 1);
}

// per-block exclusive scan (256 elems/block) + block totals
__global__ __launch_bounds__(256) void k_scan1(const int* __restrict__ cnt,
                                               int* __restrict__ lpre,
                                               int* __restrict__ bsum) {
  const int i = blockIdx.x * 256 + threadIdx.x;
  const int t = threadIdx.x, lane = t & 63, wid = t >> 6;
  int v = cnt[i];
  int x = v;
#pragma unroll
  for (int d = 1; d < 64; d <<= 1) {
    int y = __shfl_up(x, d);
    if (lane >= d) x += y;
  }
  __shared__ int wsum[4];
  if (lane == 63) wsum[wid] = x;
  __syncthreads();
  int add = 0;
#pragma unroll
  for (int wv = 0; wv < 4; wv++) add += (wv < wid) ? wsum[wv] : 0;
  lpre[i] = x + add - v;
  if (t == 255) bsum[blockIdx.x] = x + add;
}

// exclusive scan of block totals (nb <= 512), one block
__global__ __launch_bounds__(512) void k_scan2(int* __restrict__ bsum, int nb) {
  const int t = threadIdx.x, lane = t & 63, wid = t >> 6;
  int v = (t < nb) ? bsum[t] : 0;
  int x = v;
#pragma unroll
  for (int d = 1; d < 64; d <<= 1) {
    int y = __shfl_up(x, d);
    if (lane >= d) x += y;
  }
  __shared__ int wsum[8];
  if (lane == 63) wsum[wid] = x;
  __syncthreads();
  int add = 0;
#pragma unroll
  for (int wv = 0; wv < 8; wv++) add += (wv < wid) ? wsum[wv] : 0;
  if (t < nb) bsum[t] = x + add - v;
}

__global__ void k_place(const int* __restrict__ pinv, const int* __restrict__ lpre,
                        const int* __restrict__ bsum, int* __restrict__ cursor,
                        int* __restrict__ idxl, int M) {
  int m = blockIdx.x * 256 + threadIdx.x;
  if (m < M) {
    int n = pinv[m];
    int slot = atomicAdd(&cursor[n], 1);
    idxl[lpre[n] + bsum[n >> 8] + slot] = m;
  }
}

// --------------------- K1: LN(feat) -> qkv GEMM (bf16 out) -----------------
// 32-row tile, 256 thr. LDS = 8 KB h + 24 KB out stage = 32 KB.
__global__ __launch_bounds__(256) void k1_ln_qkv(
    const float* __restrict__ feat, const float* __restrict__ g1,
    const float* __restrict__ b1, const short* __restrict__ wq,
    const float* __restrict__ bq, short* __restrict__ qkvb) {
  __shared__ short h_lds[32 * 128];
  __shared__ short o_st[32 * 384];
  const int blk = blockIdx.x, t = threadIdx.x;
  {
    const int r = t >> 3, oct = t & 7;
    const float* fp = feat + (size_t)(blk * 32 + r) * 128 + oct * 16;
    float vals[16];
    float s = 0.f, s2 = 0.f;
#pragma unroll
    for (int i = 0; i < 4; i++) {
      f32x4 v = *(const f32x4*)(fp + i * 4);
#pragma unroll
      for (int j = 0; j < 4; j++) { float x = v[j]; vals[i * 4 + j] = x; s += x; s2 += x * x; }
    }
    s += __shfl_xor(s, 1);  s += __shfl_xor(s, 2);  s += __shfl_xor(s, 4);
    s2 += __shfl_xor(s2, 1); s2 += __shfl_xor(s2, 2); s2 += __shfl_xor(s2, 4);
    float mean = s * (1.f / 128.f);
    float rstd = rsqrtf(s2 * (1.f / 128.f) - mean * mean + 1e-5f);
    const int sw = (r & 7) << 4;
#pragma unroll
    for (int gi = 0; gi < 2; gi++) {
      bf16x8 wv;
#pragma unroll
      for (int j = 0; j < 8; j++) {
        int c = oct * 16 + gi * 8 + j;
        wv[j] = f2bf((vals[gi * 8 + j] - mean) * rstd * g1[c] + b1[c]);
      }
      *(bf16x8*)((char*)h_lds + r * 256 + ((oct * 32 + gi * 16) ^ sw)) = wv;
    }
  }
  __syncthreads();
  const int wave = t >> 6, lane = t & 63, u = lane & 15, g = lane >> 4;
  f32x4 acc[2][6];
  f32x4 zz = {0.f, 0.f, 0.f, 0.f};
#pragma unroll
  for (int a = 0; a < 2; a++)
#pragma unroll
    for (int b = 0; b < 6; b++) acc[a][b] = zz;
#pragma unroll
  for (int kk = 0; kk < 4; kk++) {
    bf16x8 af[2];
#pragma unroll
    for (int rt = 0; rt < 2; rt++)
      af[rt] = *(const bf16x8*)((char*)h_lds + (rt * 16 + u) * 256 +
                                ((kk * 64 + g * 16) ^ ((u & 7) << 4)));
    bf16x8 bfr[6];
#pragma unroll
    for (int ct = 0; ct < 6; ct++) {
      int col = wave * 96 + ct * 16 + u;
      bfr[ct] = *(const bf16x8*)(wq + (size_t)col * 128 + kk * 32 + g * 8);
    }
#pragma unroll
    for (int rt = 0; rt < 2; rt++)
#pragma unroll
      for (int ct = 0; ct < 6; ct++) acc[rt][ct] = MFMA(af[rt], bfr[ct], acc[rt][ct]);
  }
#pragma unroll
  for (int rt = 0; rt < 2; rt++)
#pragma unroll
    for (int ct = 0; ct < 6; ct++) {
      int col = wave * 96 + ct * 16 + u;
      float bias = bq[col];
#pragma unroll
      for (int reg = 0; reg < 4; reg++) {
        int rowl = rt * 16 + 4 * g + reg;
        *(short*)((char*)o_st + rowl * 768 + ((col * 2) ^ (g << 5))) =
            f2bf(acc[rt][ct][reg] + bias);
      }
    }
  __syncthreads();
  for (int idx = t; idx < 1536; idx += 256) {
    int r = idx / 48, c8 = idx % 48;
    bf16x8 v = *(const bf16x8*)((char*)o_st + r * 768 +
                                ((c8 * 16) ^ ((((r >> 2) & 3)) << 5)));
    *(bf16x8*)(qkvb + ((size_t)blk * 32 + r) * 384 + c8 * 8) = v;
  }
}

// --------------------- K2: windowed attention per 48-block -----------------
__global__ __launch_bounds__(512) void k2_attn(
    const short* __restrict__ qkv, const float* __restrict__ cosb,
    const float* __restrict__ sinb, const int* __restrict__ pinv,
    const int* __restrict__ padv, const int* __restrict__ unpadv,
    short* __restrict__ ocmp) {
  __shared__ short qo_lds[48 * 136];  // q: 256 B row stride; o: 272 B stride
  __shared__ short k_lds[48 * 128];
  __shared__ short vT[8 * 16 * 64];   // [h][d][j], j padded to 64
  __shared__ int midx_s[48];
  __shared__ int gidx_s[48];
  __shared__ int canon_s[48];
  __shared__ float cs_s[48 * 8];
  __shared__ float sn_s[48 * 8];

  const int w = blockIdx.x;
  const int t = threadIdx.x;

  if (t < 48) {
    int pp = w * 48 + t;
    int m = padv[pp];
    midx_s[t] = m;
    gidx_s[t] = pinv[m];
    canon_s[t] = (unpadv[m] == pp) ? 1 : 0;
    const float* cp = cosb + (size_t)m * 16;
    const float* sp = sinb + (size_t)m * 16;
#pragma unroll
    for (int i = 0; i < 2; i++) {
      *(f32x4*)(cs_s + t * 8 + i * 4) = *(const f32x4*)(cp + i * 4);
      *(f32x4*)(sn_s + t * 8 + i * 4) = *(const f32x4*)(sp + i * 4);
    }
  }
  __syncthreads();

  {  // stage qkv rows with RoPE; V goes in transposed
    const int r = t >> 3, seg = t & 7;
    if (r < 48) {
      const short* rowp = qkv + (size_t)gidx_s[r] * 384;
#pragma unroll
      for (int ci = 0; ci < 3; ci++) {
        const int c0 = seg * 48 + ci * 16;
        const int sec = c0 >> 7;
        const int hh = (c0 & 127) >> 4;
        bf16x8 lo = *(const bf16x8*)(rowp + c0);
        bf16x8 hi = *(const bf16x8*)(rowp + c0 + 8);
        if (sec < 2) {
          bf16x8 w0, w1;
#pragma unroll
          for (int j = 0; j < 8; j++) {
            float x1 = bf2f(lo[j]), x2 = bf2f(hi[j]);
            float cp = cs_s[r * 8 + j], sp2 = sn_s[r * 8 + j];
            w0[j] = f2bf(x1 * cp - x2 * sp2);
            w1[j] = f2bf(x2 * cp + x1 * sp2);
          }
          char* dst = (char*)(sec == 0 ? qo_lds : k_lds);
          int sw = (r & 7) << 4;
          *(bf16x8*)(dst + r * 256 + ((hh * 32) ^ sw)) = w0;
          *(bf16x8*)(dst + r * 256 + ((hh * 32 + 16) ^ sw)) = w1;
        } else {
#pragma unroll
          for (int d = 0; d < 16; d++) {
            short val = (d < 8) ? lo[d] : hi[d - 8];
            *(short*)((char*)vT + hh * 2048 + d * 128 + ((r * 2) ^ ((d & 7) << 3))) = val;
          }
        }
      }
    } else {  // r in 48..63: zero the V j-padding
#pragma unroll
      for (int ci = 0; ci < 3; ci++) {
        const int c0 = seg * 48 + ci * 16;
        if (c0 >= 256) {
          const int hh = (c0 & 127) >> 4;
#pragma unroll
          for (int d = 0; d < 16; d++)
            *(short*)((char*)vT + hh * 2048 + d * 128 + ((r * 2) ^ ((d & 7) << 3))) = 0;
        }
      }
    }
  }
  __syncthreads();

  const int h = t >> 6, lane = t & 63, u = lane & 15, g = lane >> 4;
  const int sbase = h * 32 + g * 16;
  bf16x8 zf = {0, 0, 0, 0, 0, 0, 0, 0};
  bf16x8 kf[3], qf[3];
#pragma unroll
  for (int i = 0; i < 3; i++) {
    int kj = i * 16 + u;
    if (g < 2) {
      kf[i] = *(const bf16x8*)((char*)k_lds + kj * 256 + (sbase ^ ((kj & 7) << 4)));
      qf[i] = *(const bf16x8*)((char*)qo_lds + kj * 256 + (sbase ^ ((kj & 7) << 4)));
    } else { kf[i] = zf; qf[i] = zf; }
  }
  union UU { bf16x8 v8; bf16x4 v4[2]; };
  UU a1, a2;
  {
    const int dbase = h * 2048 + u * 128;
    const int sw = (u & 7) << 3;
    a1.v4[0] = *(const bf16x4*)((char*)vT + dbase + ((8 * g) ^ sw));
    a1.v4[1] = *(const bf16x4*)((char*)vT + dbase + ((32 + 8 * g) ^ sw));
    a2.v4[0] = *(const bf16x4*)((char*)vT + dbase + ((64 + 8 * g) ^ sw));
    a2.v4[1] = *(const bf16x4*)((char*)vT + dbase + ((96 + 8 * g) ^ sw));
  }
  __syncthreads();  // all LDS reads done; qo_lds may now be overwritten

  f32x4 d1[3][3];
#pragma unroll
  for (int a = 0; a < 3; a++)
#pragma unroll
    for (int b = 0; b < 3; b++) {
      f32x4 z = {0.f, 0.f, 0.f, 0.f};
      d1[a][b] = MFMA(kf[a], qf[b], z);  // D1[kj][q] (scores^T)
    }

  float rl[3];
#pragma unroll
  for (int qt = 0; qt < 3; qt++) {
    float mx = -3.0e38f;
#pragma unroll
    for (int kt = 0; kt < 3; kt++)
#pragma unroll
      for (int rr = 0; rr < 4; rr++) {
        float sv = d1[kt][qt][rr] * 0.25f;
        d1[kt][qt][rr] = sv;
        mx = fmaxf(mx, sv);
      }
    mx = fmaxf(mx, __shfl_xor(mx, 16));
    mx = fmaxf(mx, __shfl_xor(mx, 32));
    float sm = 0.f;
#pragma unroll
    for (int kt = 0; kt < 3; kt++)
#pragma unroll
      for (int rr = 0; rr < 4; rr++) {
        float e = __expf(d1[kt][qt][rr] - mx);
        d1[kt][qt][rr] = e;
        sm += e;
      }
    sm += __shfl_xor(sm, 16);
    sm += __shfl_xor(sm, 32);
    rl[qt] = 1.0f / sm;
  }

#pragma unroll
  for (int qt = 0; qt < 3; qt++) {
    UU bu1, bu2;
#pragma unroll
    for (int i = 0; i < 4; i++) {
      bu1.v8[i] = f2bf(d1[0][qt][i]);
      bu1.v8[i + 4] = f2bf(d1[1][qt][i]);
      bu2.v8[i] = f2bf(d1[2][qt][i]);
      bu2.v8[i + 4] = 0;
    }
    f32x4 z = {0.f, 0.f, 0.f, 0.f};
    f32x4 acc = MFMA(a1.v8, bu1.v8, z);
    acc = MFMA(a2.v8, bu2.v8, acc);  // o^T[d][q]
#pragma unroll
    for (int reg = 0; reg < 4; reg++)
      *(short*)((char*)qo_lds + (qt * 16 + u) * 272 + h * 32 + g * 8 + reg * 2) =
          f2bf(acc[reg] * rl[qt]);
  }
  __syncthreads();
  for (int idx = t; idx < 768; idx += 512) {
    int r = idx >> 4, c8 = idx & 15;
    if (canon_s[r]) {
      *(bf16x8*)(ocmp + (size_t)midx_s[r] * 128 + c8 * 8) =
          *(const bf16x8*)((char*)qo_lds + r * 272 + c8 * 16);
    }
  }
}

// --------------- K3: proj GEMM -> oproj bf16 (coalesced, no atomics) -------
__global__ __launch_bounds__(256) void k3_proj(
    const short* __restrict__ ocmp, const short* __restrict__ wp,
    const float* __restrict__ pb, short* __restrict__ oproj, int M) {
  __shared__ short o_st[64 * 128];
  const int blk = blockIdx.x, t = threadIdx.x;
  const int m0 = blk * 64;
  const int wave = t >> 6, lane = t & 63, u = lane & 15, g = lane >> 4;
  f32x4 acc[4][2];
  f32x4 zz = {0.f, 0.f, 0.f, 0.f};
#pragma unroll
  for (int a = 0; a < 4; a++) { acc[a][0] = zz; acc[a][1] = zz; }
  bf16x8 zf = {0, 0, 0, 0, 0, 0, 0, 0};
#pragma unroll
  for (int kk = 0; kk < 4; kk++) {
    bf16x8 af[4];
#pragma unroll
    for (int rt = 0; rt < 4; rt++) {
      int m = m0 + rt * 16 + u;
      af[rt] = (m < M) ? *(const bf16x8*)(ocmp + (size_t)m * 128 + kk * 32 + g * 8) : zf;
    }
    bf16x8 bfr[2];
#pragma unroll
    for (int ct = 0; ct < 2; ct++) {
      int col = wave * 32 + ct * 16 + u;
      bfr[ct] = *(const bf16x8*)(wp + (size_t)col * 128 + kk * 32 + g * 8);
    }
#pragma unroll
    for (int rt = 0; rt < 4; rt++)
#pragma unroll
      for (int ct = 0; ct < 2; ct++) acc[rt][ct] = MFMA(af[rt], bfr[ct], acc[rt][ct]);
  }
#pragma unroll
  for (int rt = 0; rt < 4; rt++)
#pragma unroll
    for (int ct = 0; ct < 2; ct++) {
      int col = wave * 32 + ct * 16 + u;
      float bias = pb[col];
#pragma unroll
      for (int reg = 0; reg < 4; reg++) {
        int rowl = rt * 16 + 4 * g + reg;
        *(short*)((char*)o_st + rowl * 256 + ((col * 2) ^ (g << 5))) =
            f2bf(acc[rt][ct][reg] + bias);
      }
    }
  __syncthreads();
#pragma unroll
  for (int it = 0; it < 4; it++) {
    int idx = t + it * 256;
    int r = idx >> 4, c8 = idx & 15;
    if (m0 + r < M) {
      bf16x8 v = *(const bf16x8*)((char*)o_st + r * 256 +
                                  ((c8 * 16) ^ (((r >> 2) & 3) << 5)));
      *(bf16x8*)(oproj + (size_t)(m0 + r) * 128 + c8 * 8) = v;
    }
  }
}

// --- K4: gather-mean -> x -> LN2 -> fc1+GELU (LDS) -> fc2 -> residual out --
// 32-row tile, 256 thr. LDS: 32 KB tile, low 8 KB doubles as the LN(h) tile.
__global__ __launch_bounds__(256) void k4_fused(
    const float* __restrict__ feat, float* __restrict__ dout,
    const int* __restrict__ cnt, const int* __restrict__ lpre,
    const int* __restrict__ bsum, const int* __restrict__ idxl,
    const short* __restrict__ oproj,
    const float* __restrict__ g2, const float* __restrict__ b2,
    const short* __restrict__ w1, const float* __restrict__ bb1,
    const short* __restrict__ w2, const float* __restrict__ bb2) {
  __shared__ short m_lds[32 * 512];  // 32 KB; bytes [0,8K) also host h tile
  const int blk = blockIdx.x, t = threadIdx.x;
  const int wave = t >> 6, lane = t & 63, u = lane & 15, g = lane >> 4;

  // phase 1: gather segment-mean, x = feat + a, write x, LN -> h (low 8 KB)
  {
    const int r = t >> 3, oct = t & 7;
    const int n = blk * 32 + r;
    const int c = cnt[n];
    const int start = lpre[n] + bsum[n >> 8];
    float sum[16];
#pragma unroll
    for (int i = 0; i < 16; i++) sum[i] = 0.f;
    for (int j = 0; j < c; j++) {
      int m = idxl[start + j];
      const short* op = oproj + (size_t)m * 128 + oct * 16;
      bf16x8 v0 = *(const bf16x8*)op;
      bf16x8 v1 = *(const bf16x8*)(op + 8);
#pragma unroll
      for (int q = 0; q < 8; q++) { sum[q] += bf2f(v0[q]); sum[8 + q] += bf2f(v1[q]); }
    }
    const float rc = 1.0f / fmaxf((float)c, 1.0f);
    const float* fp = feat + (size_t)n * 128 + oct * 16;
    float* xp = dout + (size_t)n * 128 + oct * 16;
    float vals[16];
    float s = 0.f, s2 = 0.f;
#pragma unroll
    for (int i = 0; i < 4; i++) {
      f32x4 fv = *(const f32x4*)(fp + i * 4);
      f32x4 xv;
#pragma unroll
      for (int j = 0; j < 4; j++) {
        float x = fv[j] + sum[i * 4 + j] * rc;
        xv[j] = x; vals[i * 4 + j] = x; s += x; s2 += x * x;
      }
      *(f32x4*)(xp + i * 4) = xv;
    }
    s += __shfl_xor(s, 1);  s += __shfl_xor(s, 2);  s += __shfl_xor(s, 4);
    s2 += __shfl_xor(s2, 1); s2 += __shfl_xor(s2, 2); s2 += __shfl_xor(s2, 4);
    float mean = s * (1.f / 128.f);
    float rstd = rsqrtf(s2 * (1.f / 128.f) - mean * mean + 1e-5f);
    const int sw = (r & 7) << 4;
#pragma unroll
    for (int gi = 0; gi < 2; gi++) {
      bf16x8 wv;
#pragma unroll
      for (int j = 0; j < 8; j++) {
        int cc = oct * 16 + gi * 8 + j;
        wv[j] = f2bf((vals[gi * 8 + j] - mean) * rstd * g2[cc] + b2[cc]);
      }
      *(bf16x8*)((char*)m_lds + r * 256 + ((oct * 32 + gi * 16) ^ sw)) = wv;
    }
  }
  __syncthreads();

  // phase 2: fc1 (32x128 @ 128x512)
  f32x4 acc[2][8];
  f32x4 zz = {0.f, 0.f, 0.f, 0.f};
#pragma unroll
  for (int a = 0; a < 2; a++)
#pragma unroll
    for (int b = 0; b < 8; b++) acc[a][b] = zz;
#pragma unroll
  for (int kk = 0; kk < 4; kk++) {
    bf16x8 af[2];
#pragma unroll
    for (int rt = 0; rt < 2; rt++)
      af[rt] = *(const bf16x8*)((char*)m_lds + (rt * 16 + u) * 256 +
                                ((kk * 64 + g * 16) ^ ((u & 7) << 4)));
    bf16x8 bfr[8];
#pragma unroll
    for (int ct = 0; ct < 8; ct++) {
      int col = wave * 128 + ct * 16 + u;
      bfr[ct] = *(const bf16x8*)(w1 + (size_t)col * 128 + kk * 32 + g * 8);
    }
#pragma unroll
    for (int rt = 0; rt < 2; rt++)
#pragma unroll
      for (int ct = 0; ct < 8; ct++) acc[rt][ct] = MFMA(af[rt], bfr[ct], acc[rt][ct]);
  }
  __syncthreads();  // all h reads done; m_lds may be overwritten

  // phase 3: GELU -> stage m tile (32x512 bf16, T2 row-XOR swizzle)
#pragma unroll
  for (int rt = 0; rt < 2; rt++)
#pragma unroll
    for (int ct = 0; ct < 8; ct++) {
      int col = wave * 128 + ct * 16 + u;
      float bias = bb1[col];
#pragma unroll
      for (int reg = 0; reg < 4; reg++) {
        int rowl = rt * 16 + 4 * g + reg;
        float v = acc[rt][ct][reg] + bias;
        v = 0.5f * v * (1.0f + erff(v * 0.70710678118654752f));  // exact GELU
        *(short*)((char*)m_lds + rowl * 1024 + ((col * 2) ^ ((rowl & 7) << 4))) = f2bf(v);
      }
    }
  __syncthreads();

  // phase 4: fc2 (32x512 @ 512x128), w2 from L2; out = x + fc2 + b
  f32x4 acc2[2][2];
#pragma unroll
  for (int a = 0; a < 2; a++) { acc2[a][0] = zz; acc2[a][1] = zz; }
#pragma unroll
  for (int kk = 0; kk < 16; kk++) {
    bf16x8 af2[2];
#pragma unroll
    for (int rt = 0; rt < 2; rt++)
      af2[rt] = *(const bf16x8*)((char*)m_lds + (rt * 16 + u) * 1024 +
                                 ((kk * 64 + g * 16) ^ ((u & 7) << 4)));
#pragma unroll
    for (int ct = 0; ct < 2; ct++) {
      int col = wave * 32 + ct * 16 + u;
      bf16x8 bfr = *(const bf16x8*)(w2 + (size_t)col * 512 + kk * 32 + g * 8);
#pragma unroll
      for (int rt = 0; rt < 2; rt++) acc2[rt][ct] = MFMA(af2[rt], bfr, acc2[rt][ct]);
    }
  }
#pragma unroll
  for (int rt = 0; rt < 2; rt++)
#pragma unroll
    for (int ct = 0; ct < 2; ct++) {
      int col = wave * 32 + ct * 16 + u;
      float bias = bb2[col];
#pragma unroll
      for (int reg = 0; reg < 4; reg++) {
        size_t rr = (size_t)blk * 32 + rt * 16 + 4 * g + reg;
        float* p = dout + rr * 128 + col;  // x written in phase 1 (L2-hot)
        *p = *p + acc2[rt][ct][reg] + bias;
      }
    }
}

// ---------------------------------------------------------------------------
extern "C" void kernel_launch(void* const* d_in, const int* in_sizes, int n_in,
                              void* d_out, int out_size, void* d_ws, size_t ws_size,
                              hipStream_t stream) {
  (void)n_in; (void)out_size; (void)ws_size;
  const float* feat   = (const float*)d_in[0];
  const float* cosb   = (const float*)d_in[1];
  const float* sinb   = (const float*)d_in[2];
  const float* g1     = (const float*)d_in[3];
  const float* b1     = (const float*)d_in[4];
  const float* qkv_w  = (const float*)d_in[5];
  const float* qkv_b  = (const float*)d_in[6];
  const float* proj_w = (const float*)d_in[7];
  const float* proj_b = (const float*)d_in[8];
  const float* g2     = (const float*)d_in[9];
  const float* b2     = (const float*)d_in[10];
  const float* fc1_w  = (const float*)d_in[11];
  const float* fc1_b  = (const float*)d_in[12];
  const float* fc2_w  = (const float*)d_in[13];
  const float* fc2_b  = (const float*)d_in[14];
  const int* pinv     = (const int*)d_in[15];
  const int* padv     = (const int*)d_in[16];
  const int* unpadv   = (const int*)d_in[17];

  const int N    = in_sizes[0] / 128;
  const int M    = in_sizes[15];
  const int Mpad = in_sizes[16];
  const int Wn   = Mpad / 48;

  float* dout = (float*)d_out;
  char* ws = (char*)d_ws;

  // ws layout (bytes):
  //  region A [0, N*384*2):  qkvb bf16 (dead after k2); then reused as:
  //      A-head [0, M*256):  oproj bf16 (k3 writes, k4 reads)
  //      A-tail [M*256,...): sort ints (written after k2: cnt,cursor,lpre,
  //                          bsum, idxlist) — fits in the 27 MB slack
  //  region B [szQ, szQ+M*256): ocmp bf16 (k2 writes, k3 reads)
  //  weights bf16 after B. Peak ~175 MB (same as before).
  size_t szQ = (size_t)N * 384 * 2;
  size_t szO = (size_t)M * 128 * 2;

  short* qkvb  = (short*)ws;
  short* oproj = (short*)ws;
  short* ocmp  = (short*)(ws + szQ);

  size_t offI = ((size_t)M * 256 + 255) & ~(size_t)255;  // A-tail start
  int* cnt    = (int*)(ws + offI);
  int* cursor = cnt + N;
  int* lpre   = cursor + N;
  int* bsum   = lpre + N;       // 512 used (+pad)
  int* idxl   = bsum + 1024;

  size_t offW = szQ + szO;
  short* wq_b = (short*)(ws + offW);
  short* wp_b = wq_b + 49152;
  short* w1_b = wp_b + 16384;
  short* w2_b = w1_b + 65536;

  k_cvt<<<(49152 + 255) / 256, 256, 0, stream>>>(qkv_w, wq_b, 49152);
  k_cvt<<<(16384 + 255) / 256, 256, 0, stream>>>(proj_w, wp_b, 16384);
  k_cvt<<<(65536 + 255) / 256, 256, 0, stream>>>(fc1_w, w1_b, 65536);
  k_cvt<<<(65536 + 255) / 256, 256, 0, stream>>>(fc2_w, w2_b, 65536);

  k1_ln_qkv<<<N / 32, 256, 0, stream>>>(feat, g1, b1, wq_b, qkv_b, qkvb);
  k2_attn<<<Wn, 512, 0, stream>>>(qkvb, cosb, sinb, pinv, padv, unpadv, ocmp);

  // counting sort of pinv (storage aliases qkvb's tail — dead after k2)
  hipMemsetAsync(cnt, 0, (size_t)N * 4, stream);
  hipMemsetAsync(cursor, 0, (size_t)N * 4, stream);
  k_cnt<<<(M + 255) / 256, 256, 0, stream>>>(pinv, cnt, M);
  k_scan1<<<N / 256, 256, 0, stream>>>(cnt, lpre, bsum);
  k_scan2<<<1, 512, 0, stream>>>(bsum, N / 256);
  k_place<<<(M + 255) / 256, 256, 0, stream>>>(pinv, lpre, bsum, cursor, idxl, M);

  k3_proj<<<(M + 63) / 64, 256, 0, stream>>>(ocmp, wp_b, proj_b, oproj, M);
  k4_fused<<<N / 32, 256, 0, stream>>>(feat, dout, cnt, lpre, bsum, idxl, oproj,
                                       g2, b2, w1_b, fc1_b, w2_b, fc2_b);
}